// Round 8
// baseline (724.497 us; speedup 1.0000x reference)
//
#include <hip/hip_runtime.h>

typedef __bf16 bf16_t;
typedef __bf16 bf16x8 __attribute__((ext_vector_type(8)));
typedef __bf16 bf16x4 __attribute__((ext_vector_type(4)));
typedef float f32x4 __attribute__((ext_vector_type(4)));

#define BM 128
#define BN 128
#define BK 64
// LDS layout: per row of 8 x 16B chunks, chunk cc is stored at slot (cc ^ (row&7)).
// DMA writes base + lane*16 contiguously (m104/m108): we permute WHICH global
// chunk each lane loads; fragment ds_read_b128s then spread over all 32 banks.

__device__ __forceinline__ void gload_lds16(const void* g, void* s) {
    __builtin_amdgcn_global_load_lds(
        (const __attribute__((address_space(1))) unsigned int*)g,
        (__attribute__((address_space(3))) unsigned int*)s, 16, 0, 0);
}

// ---------------- GEMM: C = A[M,K](bf16) * Bt[Ntot,K]^T (bf16), fp32 acc ----------------
__global__ __launch_bounds__(256) void gemm_k(
    const bf16_t* __restrict__ A, int lda, int M,
    const bf16_t* __restrict__ Bt, int K,
    const float* __restrict__ bias, int relu_flag,
    bf16_t* __restrict__ outb, int ldo, int ocol,
    int NTM, int NTN)
{
    __shared__ __align__(16) bf16_t As[BM * BK];   // 16 KB
    __shared__ __align__(16) bf16_t Bs[BN * BK];   // 16 KB

    const int L    = blockIdx.x;
    const int xcd  = L & 7;
    const int rest = L >> 3;
    const int nt   = rest % NTN;
    const int sup  = rest / NTN;
    const int mt   = sup * 8 + xcd;
    if (mt >= NTM) return;
    const int m0 = mt * BM;
    const int n0 = nt * BN;

    const int tid  = threadIdx.x;
    const int wave = tid >> 6, lane = tid & 63;
    const int wr   = wave >> 1, wc = wave & 1;
    const int lm   = lane & 15, quad = lane >> 4;

    const bf16_t* ag[4];
    const bf16_t* bg[4];
    #pragma unroll
    for (int j = 0; j < 4; j++) {
        int c    = wave * 256 + j * 64 + lane;
        int row  = c >> 3;
        int cc   = (c & 7) ^ (row & 7);
        int col  = cc << 3;
        int gm   = m0 + row; if (gm >= M) gm = M - 1;
        ag[j] = A  + (size_t)gm * lda + col;
        bg[j] = Bt + (size_t)(n0 + row) * K + col;
    }

    f32x4 acc[4][4] = {};

    for (int k0 = 0; k0 < K; k0 += BK) {
        __syncthreads();
        #pragma unroll
        for (int j = 0; j < 4; j++)
            gload_lds16(ag[j] + k0, As + (size_t)(wave * 256 + j * 64) * 8);
        #pragma unroll
        for (int j = 0; j < 4; j++)
            gload_lds16(bg[j] + k0, Bs + (size_t)(wave * 256 + j * 64) * 8);
        __syncthreads();

        #pragma unroll
        for (int h = 0; h < 2; h++) {
            bf16x8 af[4], bfr[4];
            #pragma unroll
            for (int i = 0; i < 4; i++) {
                int r = wr * 64 + i * 16 + lm;
                af[i] = *(const bf16x8*)&As[(size_t)(r * 8 + ((h * 4 + quad) ^ (r & 7))) * 8];
            }
            #pragma unroll
            for (int i = 0; i < 4; i++) {
                int r = wc * 64 + i * 16 + lm;
                bfr[i] = *(const bf16x8*)&Bs[(size_t)(r * 8 + ((h * 4 + quad) ^ (r & 7))) * 8];
            }
            #pragma unroll
            for (int mi = 0; mi < 4; mi++)
                #pragma unroll
                for (int ni = 0; ni < 4; ni++)
                    acc[mi][ni] = __builtin_amdgcn_mfma_f32_16x16x32_bf16(
                        af[mi], bfr[ni], acc[mi][ni], 0, 0, 0);
        }
    }

    #pragma unroll
    for (int mi = 0; mi < 4; mi++) {
        #pragma unroll
        for (int ni = 0; ni < 4; ni++) {
            int col = n0 + wc * 64 + ni * 16 + lm;
            float b = bias[col];
            #pragma unroll
            for (int r = 0; r < 4; r++) {
                int row = m0 + wr * 64 + mi * 16 + quad * 4 + r;
                if (row < M) {
                    float v = acc[mi][ni][r] + b;
                    if (relu_flag) v = fmaxf(v, 0.f);
                    outb[(size_t)row * ldo + ocol + col] = (bf16_t)v;
                }
            }
        }
    }
}

// ---------------- CSR build ----------------
__global__ void count_k(const int* __restrict__ dst, const int* __restrict__ rel,
                        int* __restrict__ cnt, int E)
{
    int e = blockIdx.x * blockDim.x + threadIdx.x;
    if (e < E) atomicAdd(&cnt[dst[e] * 4 + rel[e]], 1);
}

__global__ void scan_partial(const int* __restrict__ cnt, int* __restrict__ offs,
                             int* __restrict__ chunkSums, int NSEG)
{
    __shared__ int sh[256];
    int t = threadIdx.x;
    int idx = blockIdx.x * 256 + t;
    int v = (idx < NSEG) ? cnt[idx] : 0;
    sh[t] = v;
    __syncthreads();
    for (int d = 1; d < 256; d <<= 1) {
        int add = (t >= d) ? sh[t - d] : 0;
        __syncthreads();
        sh[t] += add;
        __syncthreads();
    }
    if (idx < NSEG) offs[idx] = sh[t] - v;
    if (t == 255) chunkSums[blockIdx.x] = sh[t];
}

__global__ void scan_chunks(int* __restrict__ chunkSums, int NCHUNK)
{
    __shared__ int sh[1024];
    int t = threadIdx.x;
    int v = (t < NCHUNK) ? chunkSums[t] : 0;
    sh[t] = v;
    __syncthreads();
    for (int d = 1; d < 1024; d <<= 1) {
        int add = (t >= d) ? sh[t - d] : 0;
        __syncthreads();
        sh[t] += add;
        __syncthreads();
    }
    if (t < NCHUNK) chunkSums[t] = sh[t] - v;
}

__global__ void scan_add(int* __restrict__ offs, const int* __restrict__ chunkSums,
                         int* __restrict__ cursor, int NSEG)
{
    int idx = blockIdx.x * 256 + threadIdx.x;
    if (idx < NSEG) {
        int o = offs[idx] + chunkSums[blockIdx.x];
        offs[idx] = o;
        cursor[idx] = o;
    }
}

__global__ void fill_k(const int* __restrict__ src, const int* __restrict__ dst,
                       const int* __restrict__ rel,
                       int* __restrict__ cursor, int* __restrict__ eidx, int E)
{
    int e = blockIdx.x * blockDim.x + threadIdx.x;
    if (e < E) {
        int seg = dst[e] * 4 + rel[e];
        int pos = atomicAdd(&cursor[seg], 1);
        eidx[pos] = src[e];
    }
}

// ---------------- segment mean, D=256, XCD-column-sliced ----------------
// blockIdx&7 selects a 32-col slice -> all blocks of slice k land on XCD k
// (round-robin heuristic), so each XCD's L2 only caches a 3.2 MB table slice.
// Wave: 4 segments x 4 edges x 4 lane-colgroups (8 cols x bf16x8 per lane).
__global__ void seg_mean256(const int* __restrict__ offs, const int* __restrict__ cnt,
                            const int* __restrict__ eidx,
                            const bf16_t* __restrict__ xb, int ldx,
                            bf16_t* __restrict__ Aout, int lda, int NSEG)
{
    const int slice = blockIdx.x & 7;
    const int wave  = threadIdx.x >> 6, lane = threadIdx.x & 63;
    const int seg   = (blockIdx.x >> 3) * 16 + wave * 4 + (lane >> 4);
    const int esub  = (lane >> 2) & 3;                // edge slot 0..3
    const int cb    = slice * 32 + (lane & 3) * 8;    // column base
    if (seg >= NSEG) return;
    const int start = offs[seg];
    const int n     = cnt[seg];
    float acc[8] = {};
    for (int i = 0; i < n; i += 4) {
        int e = i + esub;
        if (e < n) {
            int s = eidx[start + e];
            bf16x8 v = *(const bf16x8*)(xb + (size_t)s * ldx + cb);
            #pragma unroll
            for (int j = 0; j < 8; j++) acc[j] += (float)v[j];
        }
    }
    #pragma unroll
    for (int j = 0; j < 8; j++) {                     // reduce over edge slots
        acc[j] += __shfl_xor(acc[j], 4, 64);
        acc[j] += __shfl_xor(acc[j], 8, 64);
    }
    if (esub == 0) {
        float inv = 1.0f / ((float)n + 1e-10f);
        int node = seg >> 2, r = seg & 3;
        bf16x8 o;
        #pragma unroll
        for (int j = 0; j < 8; j++) o[j] = (bf16_t)(acc[j] * inv);
        *(bf16x8*)(Aout + (size_t)node * lda + r * 256 + cb) = o;
    }
}

// ---------------- segment mean, D=128, XCD-column-sliced (8 x 16-col slices) --
// Wave: 4 segments x 8 edges x 2 lane-colgroups (8 cols x bf16x8 per lane).
__global__ void seg_mean128(const int* __restrict__ offs, const int* __restrict__ cnt,
                            const int* __restrict__ eidx,
                            const bf16_t* __restrict__ xb, int ldx,
                            bf16_t* __restrict__ Aout, int lda, int NSEG)
{
    const int slice = blockIdx.x & 7;
    const int wave  = threadIdx.x >> 6, lane = threadIdx.x & 63;
    const int seg   = (blockIdx.x >> 3) * 16 + wave * 4 + (lane >> 4);
    const int esub  = (lane >> 1) & 7;                // edge slot 0..7
    const int cb    = slice * 16 + (lane & 1) * 8;    // column base
    if (seg >= NSEG) return;
    const int start = offs[seg];
    const int n     = cnt[seg];
    float acc[8] = {};
    for (int i = 0; i < n; i += 8) {
        int e = i + esub;
        if (e < n) {
            int s = eidx[start + e];
            bf16x8 v = *(const bf16x8*)(xb + (size_t)s * ldx + cb);
            #pragma unroll
            for (int j = 0; j < 8; j++) acc[j] += (float)v[j];
        }
    }
    #pragma unroll
    for (int j = 0; j < 8; j++) {                     // reduce over edge slots
        acc[j] += __shfl_xor(acc[j], 2, 64);
        acc[j] += __shfl_xor(acc[j], 4, 64);
        acc[j] += __shfl_xor(acc[j], 8, 64);
    }
    if (esub == 0) {
        float inv = 1.0f / ((float)n + 1e-10f);
        int node = seg >> 2, r = seg & 3;
        bf16x8 o;
        #pragma unroll
        for (int j = 0; j < 8; j++) o[j] = (bf16_t)(acc[j] * inv);
        *(bf16x8*)(Aout + (size_t)node * lda + r * 128 + cb) = o;
    }
}

// x fp32 [N,128] -> bf16 into A1 columns 512..640 (ld 640)
__global__ void convert_x_k(const float* __restrict__ x, bf16_t* __restrict__ A1, int N)
{
    int t = blockIdx.x * blockDim.x + threadIdx.x;
    if (t >= N * 32) return;
    int row = t >> 5;
    int c = (t & 31) << 2;
    f32x4 v = *(const f32x4*)(x + (size_t)row * 128 + c);
    bf16x4 o;
    o[0] = (bf16_t)v[0]; o[1] = (bf16_t)v[1]; o[2] = (bf16_t)v[2]; o[3] = (bf16_t)v[3];
    *(bf16x4*)(A1 + (size_t)row * 640 + 512 + c) = o;
}

// Wt[(n0+n)*ldk + k0 + k] = (bf16) W[k, n];  W is [K,256] row-major
__global__ void transpose_w(const float* __restrict__ W, bf16_t* __restrict__ Wt,
                            int K, int ldk, int k0, int n0)
{
    int t = blockIdx.x * blockDim.x + threadIdx.x;
    if (t >= K * 256) return;
    int k = t >> 8, n = t & 255;
    Wt[(size_t)(n0 + n) * ldk + k0 + k] = (bf16_t)W[(size_t)k * 256 + n];
}

__global__ void prep_bias(const float* rb1, const float* lb1,
                          const float* rb2, const float* lb2,
                          const float* hpb1, const float* htb1,
                          const float* hpb2, const float* htb2,
                          float* bR1, float* bR2, float* bH1, float* bH2)
{
    int t = threadIdx.x;  // 256
    bR1[t] = rb1[t] + lb1[t];
    bR2[t] = rb2[t] + lb2[t];
    bH1[t] = hpb1[t]; bH1[256 + t] = htb1[t];
    bH2[t] = hpb2[t]; bH2[256 + t] = htb2[t];
}

// h' = sigmoid(G)*relu(P) + (1-sigmoid(G))*h ;  PG = [P | G] bf16 [N,512]
__global__ void highway_k(const bf16_t* __restrict__ PG, const bf16_t* __restrict__ h,
                          int N, bf16_t* __restrict__ outb, int ldo, int ocol,
                          float* __restrict__ outf)
{
    int t = blockIdx.x * blockDim.x + threadIdx.x;
    if (t >= N * 64) return;
    int row = t >> 6;
    int c = (t & 63) << 2;
    size_t ip = (size_t)row * 512 + c;
    bf16x4 p = *(const bf16x4*)(PG + ip);
    bf16x4 g = *(const bf16x4*)(PG + ip + 256);
    bf16x4 hv = *(const bf16x4*)(h + (size_t)row * 256 + c);
    bf16x4 ob;
    f32x4 of;
    #pragma unroll
    for (int j = 0; j < 4; j++) {
        float gg = 1.0f / (1.0f + __expf(-(float)g[j]));
        float pp = fmaxf((float)p[j], 0.f);
        float v = gg * pp + (1.0f - gg) * (float)hv[j];
        ob[j] = (bf16_t)v;
        of[j] = v;
    }
    if (outb) *(bf16x4*)(outb + (size_t)row * ldo + ocol + c) = ob;
    if (outf) *(f32x4*)(outf + (size_t)row * 256 + c) = of;
}

extern "C" void kernel_launch(void* const* d_in, const int* in_sizes, int n_in,
                              void* d_out, int out_size, void* d_ws, size_t ws_size,
                              hipStream_t stream)
{
    const float* x       = (const float*)d_in[0];
    const int*   src     = (const int*)d_in[1];
    const int*   dst     = (const int*)d_in[2];
    const int*   rel     = (const int*)d_in[3];
    const float* rel_w1  = (const float*)d_in[4];
    const float* rel_b1  = (const float*)d_in[5];
    const float* loop_w1 = (const float*)d_in[6];
    const float* loop_b1 = (const float*)d_in[7];
    const float* hp_w1   = (const float*)d_in[8];
    const float* hp_b1   = (const float*)d_in[9];
    const float* ht_w1   = (const float*)d_in[10];
    const float* ht_b1   = (const float*)d_in[11];
    const float* rel_w2  = (const float*)d_in[12];
    const float* rel_b2  = (const float*)d_in[13];
    const float* loop_w2 = (const float*)d_in[14];
    const float* loop_b2 = (const float*)d_in[15];
    const float* hp_w2   = (const float*)d_in[16];
    const float* hp_b2   = (const float*)d_in[17];
    const float* ht_w2   = (const float*)d_in[18];
    const float* ht_b2   = (const float*)d_in[19];

    const int N = in_sizes[0] / 128;   // 50000
    const int E = in_sizes[1];         // 800000
    const int NSEG = N * 4;            // 200000
    const int NCHUNK = (NSEG + 255) / 256;   // 782
    float* out = (float*)d_out;

    char* ws = (char*)d_ws;
    size_t off = 0;
    auto alloc = [&](size_t bytes) {
        void* p = ws + off;
        off += (bytes + 255) & ~(size_t)255;
        return p;
    };
    int*    cnt    = (int*)alloc((size_t)NSEG * 4);
    int*    offs   = (int*)alloc((size_t)NSEG * 4);
    int*    cursor = (int*)alloc((size_t)NSEG * 4);
    int*    chunkS = (int*)alloc(4096);
    int*    eidx   = (int*)alloc((size_t)E * 4);
    bf16_t* A1     = (bf16_t*)alloc((size_t)N * 640 * 2);    // [update1 | x_bf16]; later hosts PG
    bf16_t* A2     = (bf16_t*)alloc((size_t)N * 1280 * 2);   // [update2 | h1']
    bf16_t* h      = (bf16_t*)alloc((size_t)N * 256 * 2);
    bf16_t* W1t    = (bf16_t*)alloc((size_t)256 * 640 * 2);
    bf16_t* W2t    = (bf16_t*)alloc((size_t)256 * 1280 * 2);
    bf16_t* Wh1t   = (bf16_t*)alloc((size_t)512 * 256 * 2);
    bf16_t* Wh2t   = (bf16_t*)alloc((size_t)512 * 256 * 2);
    float*  bR1    = (float*)alloc(256 * 4);
    float*  bR2    = (float*)alloc(256 * 4);
    float*  bH1    = (float*)alloc(512 * 4);
    float*  bH2    = (float*)alloc(512 * 4);
    bf16_t* PG     = A1;   // alias: A1 dead after layer-1 RGC GEMM

    dim3 blk(256);
    const int NTM = (N + BM - 1) / BM;       // 391
    const int supers = (NTM + 7) / 8;        // 49
    const int gridRGC = supers * 8 * 2;      // 784
    const int gridHW  = supers * 8 * 4;      // 1568
    const int gridSEG = 8 * ((NSEG + 15) / 16);   // 100000 (slice-major decode)

    // ---- weight/bias prep ----
    transpose_w<<<dim3(512), blk, 0, stream>>>(rel_w1, W1t, 512, 640, 0, 0);
    transpose_w<<<dim3(128), blk, 0, stream>>>(loop_w1, W1t, 128, 640, 512, 0);
    transpose_w<<<dim3(1024), blk, 0, stream>>>(rel_w2, W2t, 1024, 1280, 0, 0);
    transpose_w<<<dim3(256), blk, 0, stream>>>(loop_w2, W2t, 256, 1280, 1024, 0);
    transpose_w<<<dim3(256), blk, 0, stream>>>(hp_w1, Wh1t, 256, 256, 0, 0);
    transpose_w<<<dim3(256), blk, 0, stream>>>(ht_w1, Wh1t, 256, 256, 0, 256);
    transpose_w<<<dim3(256), blk, 0, stream>>>(hp_w2, Wh2t, 256, 256, 0, 0);
    transpose_w<<<dim3(256), blk, 0, stream>>>(ht_w2, Wh2t, 256, 256, 0, 256);
    prep_bias<<<dim3(1), blk, 0, stream>>>(rel_b1, loop_b1, rel_b2, loop_b2,
                                           hp_b1, ht_b1, hp_b2, ht_b2,
                                           bR1, bR2, bH1, bH2);
    convert_x_k<<<dim3((N * 32 + 255) / 256), blk, 0, stream>>>(x, A1, N);

    // ---- CSR build (shared by both layers) ----
    hipMemsetAsync(cnt, 0, (size_t)NSEG * 4, stream);
    count_k<<<dim3((E + 255) / 256), blk, 0, stream>>>(dst, rel, cnt, E);
    scan_partial<<<dim3(NCHUNK), blk, 0, stream>>>(cnt, offs, chunkS, NSEG);
    scan_chunks<<<dim3(1), dim3(1024), 0, stream>>>(chunkS, NCHUNK);
    scan_add<<<dim3(NCHUNK), blk, 0, stream>>>(offs, chunkS, cursor, NSEG);
    fill_k<<<dim3((E + 255) / 256), blk, 0, stream>>>(src, dst, rel, cursor, eidx, E);

    // ---- layer 1 ----
    seg_mean128<<<dim3(gridSEG), blk, 0, stream>>>(offs, cnt, eidx,
                                                   A1 + 512, 640, A1, 640, NSEG);
    gemm_k<<<dim3(gridRGC), blk, 0, stream>>>(A1, 640, N, W1t, 640,
                                              bR1, 1, h, 256, 0, NTM, 2);
    gemm_k<<<dim3(gridHW), blk, 0, stream>>>(h, 256, N, Wh1t, 256,
                                             bH1, 0, PG, 512, 0, NTM, 4);
    highway_k<<<dim3((N * 64 + 255) / 256), blk, 0, stream>>>(PG, h, N,
                                                              A2, 1280, 1024, nullptr);

    // ---- layer 2 ----
    seg_mean256<<<dim3(gridSEG), blk, 0, stream>>>(offs, cnt, eidx,
                                                   A2 + 1024, 1280, A2, 1280, NSEG);
    gemm_k<<<dim3(gridRGC), blk, 0, stream>>>(A2, 1280, N, W2t, 1280,
                                              bR2, 1, h, 256, 0, NTM, 2);
    gemm_k<<<dim3(gridHW), blk, 0, stream>>>(h, 256, N, Wh2t, 256,
                                             bH2, 0, PG, 512, 0, NTM, 4);
    highway_k<<<dim3((N * 64 + 255) / 256), blk, 0, stream>>>(PG, h, N,
                                                              nullptr, 0, 0, out);
}

// Round 9
// 555.220 us; speedup vs baseline: 1.3049x; 1.3049x over previous
//
#include <hip/hip_runtime.h>

typedef __bf16 bf16_t;
typedef __bf16 bf16x8 __attribute__((ext_vector_type(8)));
typedef __bf16 bf16x4 __attribute__((ext_vector_type(4)));
typedef float f32x4 __attribute__((ext_vector_type(4)));

#define BM 128
#define BN 128
#define BK 64
// LDS layout: per row of 8 x 16B chunks, chunk cc is stored at slot (cc ^ (row&7)).
// DMA writes base + lane*16 contiguously (m104/m108): we permute WHICH global
// chunk each lane loads; fragment ds_read_b128s then spread over all 32 banks.

__device__ __forceinline__ void gload_lds16(const void* g, void* s) {
    __builtin_amdgcn_global_load_lds(
        (const __attribute__((address_space(1))) unsigned int*)g,
        (__attribute__((address_space(3))) unsigned int*)s, 16, 0, 0);
}

// ---------------- GEMM: C = A[M,K](bf16) * Bt[Ntot,K]^T (bf16), fp32 acc ----------------
__global__ __launch_bounds__(256) void gemm_k(
    const bf16_t* __restrict__ A, int lda, int M,
    const bf16_t* __restrict__ Bt, int K,
    const float* __restrict__ bias, int relu_flag,
    bf16_t* __restrict__ outb, int ldo, int ocol,
    int NTM, int NTN)
{
    __shared__ __align__(16) bf16_t As[BM * BK];   // 16 KB
    __shared__ __align__(16) bf16_t Bs[BN * BK];   // 16 KB

    const int L    = blockIdx.x;
    const int xcd  = L & 7;
    const int rest = L >> 3;
    const int nt   = rest % NTN;
    const int sup  = rest / NTN;
    const int mt   = sup * 8 + xcd;
    if (mt >= NTM) return;
    const int m0 = mt * BM;
    const int n0 = nt * BN;

    const int tid  = threadIdx.x;
    const int wave = tid >> 6, lane = tid & 63;
    const int wr   = wave >> 1, wc = wave & 1;
    const int lm   = lane & 15, quad = lane >> 4;

    const bf16_t* ag[4];
    const bf16_t* bg[4];
    #pragma unroll
    for (int j = 0; j < 4; j++) {
        int c    = wave * 256 + j * 64 + lane;
        int row  = c >> 3;
        int cc   = (c & 7) ^ (row & 7);
        int col  = cc << 3;
        int gm   = m0 + row; if (gm >= M) gm = M - 1;
        ag[j] = A  + (size_t)gm * lda + col;
        bg[j] = Bt + (size_t)(n0 + row) * K + col;
    }

    f32x4 acc[4][4] = {};

    for (int k0 = 0; k0 < K; k0 += BK) {
        __syncthreads();
        #pragma unroll
        for (int j = 0; j < 4; j++)
            gload_lds16(ag[j] + k0, As + (size_t)(wave * 256 + j * 64) * 8);
        #pragma unroll
        for (int j = 0; j < 4; j++)
            gload_lds16(bg[j] + k0, Bs + (size_t)(wave * 256 + j * 64) * 8);
        __syncthreads();

        #pragma unroll
        for (int h = 0; h < 2; h++) {
            bf16x8 af[4], bfr[4];
            #pragma unroll
            for (int i = 0; i < 4; i++) {
                int r = wr * 64 + i * 16 + lm;
                af[i] = *(const bf16x8*)&As[(size_t)(r * 8 + ((h * 4 + quad) ^ (r & 7))) * 8];
            }
            #pragma unroll
            for (int i = 0; i < 4; i++) {
                int r = wc * 64 + i * 16 + lm;
                bfr[i] = *(const bf16x8*)&Bs[(size_t)(r * 8 + ((h * 4 + quad) ^ (r & 7))) * 8];
            }
            #pragma unroll
            for (int mi = 0; mi < 4; mi++)
                #pragma unroll
                for (int ni = 0; ni < 4; ni++)
                    acc[mi][ni] = __builtin_amdgcn_mfma_f32_16x16x32_bf16(
                        af[mi], bfr[ni], acc[mi][ni], 0, 0, 0);
        }
    }

    #pragma unroll
    for (int mi = 0; mi < 4; mi++) {
        #pragma unroll
        for (int ni = 0; ni < 4; ni++) {
            int col = n0 + wc * 64 + ni * 16 + lm;
            float b = bias[col];
            #pragma unroll
            for (int r = 0; r < 4; r++) {
                int row = m0 + wr * 64 + mi * 16 + quad * 4 + r;
                if (row < M) {
                    float v = acc[mi][ni][r] + b;
                    if (relu_flag) v = fmaxf(v, 0.f);
                    outb[(size_t)row * ldo + ocol + col] = (bf16_t)v;
                }
            }
        }
    }
}

// ---------------- Fused highway GEMM+gate: occupancy-lean version ----------------
// Block: 128 rows x (64 P-cols + 64 G-cols), strip nt in 0..3.
// Each wave: 32 rows x all 128 Bs-cols -> acc[2][8] (64 acc regs, same as gemm_k).
// Bs rows: [hp rows nt*64..+63 | ht rows nt*64..+63]. Epilogue gates in-register.
__global__ __launch_bounds__(256) void gemm_hw2(
    const bf16_t* __restrict__ A, int M,          // h [M,256] bf16 (also skip input)
    const bf16_t* __restrict__ Bt,                // Wh [512,256] = [hp rows | ht rows]
    const float* __restrict__ bias,               // [512] = [hp bias | ht bias]
    bf16_t* __restrict__ outb, int ldo, int ocol,
    float* __restrict__ outf, int NTM)
{
    __shared__ __align__(16) bf16_t As[128 * 64];   // 16 KB
    __shared__ __align__(16) bf16_t Bs[128 * 64];   // 16 KB

    const int L    = blockIdx.x;
    const int xcd  = L & 7;
    const int rest = L >> 3;
    const int nt   = rest % 4;                    // 64-col strip
    const int sup  = rest / 4;
    const int mt   = sup * 8 + xcd;
    if (mt >= NTM) return;
    const int m0 = mt * 128;

    const int tid  = threadIdx.x;
    const int wave = tid >> 6, lane = tid & 63;
    const int lm   = lane & 15, quad = lane >> 4;

    const bf16_t* ag[4];
    const bf16_t* bg[4];
    #pragma unroll
    for (int j = 0; j < 4; j++) {
        int c    = wave * 256 + j * 64 + lane;    // chunk 0..1023
        int row  = c >> 3;                        // 0..127
        int cc   = (c & 7) ^ (row & 7);
        int col  = cc << 3;                       // 0..56
        int gm   = m0 + row; if (gm >= M) gm = M - 1;
        ag[j] = A + (size_t)gm * 256 + col;
        int grow = nt * 64 + row + ((row >= 64) ? 192 : 0);   // hp strip | ht strip
        bg[j] = Bt + (size_t)grow * 256 + col;
    }

    f32x4 acc[2][8] = {};

    for (int k0 = 0; k0 < 256; k0 += 64) {
        __syncthreads();
        #pragma unroll
        for (int j = 0; j < 4; j++)
            gload_lds16(ag[j] + k0, As + (size_t)(wave * 256 + j * 64) * 8);
        #pragma unroll
        for (int j = 0; j < 4; j++)
            gload_lds16(bg[j] + k0, Bs + (size_t)(wave * 256 + j * 64) * 8);
        __syncthreads();

        #pragma unroll
        for (int h = 0; h < 2; h++) {
            bf16x8 af[2], bfr[8];
            #pragma unroll
            for (int i = 0; i < 2; i++) {
                int r = wave * 32 + i * 16 + lm;
                af[i] = *(const bf16x8*)&As[(size_t)(r * 8 + ((h * 4 + quad) ^ (r & 7))) * 8];
            }
            #pragma unroll
            for (int i = 0; i < 8; i++) {
                int r = i * 16 + lm;
                bfr[i] = *(const bf16x8*)&Bs[(size_t)(r * 8 + ((h * 4 + quad) ^ (r & 7))) * 8];
            }
            #pragma unroll
            for (int mi = 0; mi < 2; mi++)
                #pragma unroll
                for (int ni = 0; ni < 8; ni++)
                    acc[mi][ni] = __builtin_amdgcn_mfma_f32_16x16x32_bf16(
                        af[mi], bfr[ni], acc[mi][ni], 0, 0, 0);
        }
    }

    // epilogue: lane holds P (ni) and G (ni+4) for identical (row,col); gate here.
    #pragma unroll
    for (int mi = 0; mi < 2; mi++) {
        #pragma unroll
        for (int ni = 0; ni < 4; ni++) {
            int col = nt * 64 + ni * 16 + lm;     // 0..255
            float bp = bias[col];
            float bg2 = bias[256 + col];
            #pragma unroll
            for (int r = 0; r < 4; r++) {
                int row = m0 + wave * 32 + mi * 16 + quad * 4 + r;
                if (row < M) {
                    float p = acc[mi][ni][r] + bp;
                    float g = acc[mi][ni + 4][r] + bg2;
                    float s = 1.0f / (1.0f + __expf(-g));
                    float hv = (float)A[(size_t)row * 256 + col];
                    float v = s * fmaxf(p, 0.f) + (1.0f - s) * hv;
                    if (outf) outf[(size_t)row * 256 + col] = v;
                    else      outb[(size_t)row * ldo + ocol + col] = (bf16_t)v;
                }
            }
        }
    }
}

// ---------------- CSR build ----------------
__global__ void count_k(const int* __restrict__ dst, const int* __restrict__ rel,
                        int* __restrict__ cnt, int E)
{
    int e = blockIdx.x * blockDim.x + threadIdx.x;
    if (e < E) atomicAdd(&cnt[dst[e] * 4 + rel[e]], 1);
}

__global__ void scan_partial(const int* __restrict__ cnt, int* __restrict__ offs,
                             int* __restrict__ chunkSums, int NSEG)
{
    __shared__ int sh[256];
    int t = threadIdx.x;
    int idx = blockIdx.x * 256 + t;
    int v = (idx < NSEG) ? cnt[idx] : 0;
    sh[t] = v;
    __syncthreads();
    for (int d = 1; d < 256; d <<= 1) {
        int add = (t >= d) ? sh[t - d] : 0;
        __syncthreads();
        sh[t] += add;
        __syncthreads();
    }
    if (idx < NSEG) offs[idx] = sh[t] - v;
    if (t == 255) chunkSums[blockIdx.x] = sh[t];
}

__global__ void scan_chunks(int* __restrict__ chunkSums, int NCHUNK)
{
    __shared__ int sh[1024];
    int t = threadIdx.x;
    int v = (t < NCHUNK) ? chunkSums[t] : 0;
    sh[t] = v;
    __syncthreads();
    for (int d = 1; d < 1024; d <<= 1) {
        int add = (t >= d) ? sh[t - d] : 0;
        __syncthreads();
        sh[t] += add;
        __syncthreads();
    }
    if (t < NCHUNK) chunkSums[t] = sh[t] - v;
}

__global__ void scan_add(int* __restrict__ offs, const int* __restrict__ chunkSums,
                         int* __restrict__ cursor, int NSEG)
{
    int idx = blockIdx.x * 256 + threadIdx.x;
    if (idx < NSEG) {
        int o = offs[idx] + chunkSums[blockIdx.x];
        offs[idx] = o;
        cursor[idx] = o;
    }
}

__global__ void fill_k(const int* __restrict__ src, const int* __restrict__ dst,
                       const int* __restrict__ rel,
                       int* __restrict__ cursor, int* __restrict__ eidx, int E)
{
    int e = blockIdx.x * blockDim.x + threadIdx.x;
    if (e < E) {
        int seg = dst[e] * 4 + rel[e];
        int pos = atomicAdd(&cursor[seg], 1);
        eidx[pos] = src[e];
    }
}

// ---------------- segment mean, D=256: half-wave/edge, bf16x8, 8-deep unroll ----
__global__ void seg_mean256(const int* __restrict__ offs, const int* __restrict__ cnt,
                            const int* __restrict__ eidx,
                            const bf16_t* __restrict__ xb, int ldx,
                            bf16_t* __restrict__ Aout, int lda, int NSEG)
{
    int wv = (blockIdx.x << 2) + (threadIdx.x >> 6);
    if (wv >= NSEG) return;
    int lane = threadIdx.x & 63;
    int half = lane >> 5;
    int c = (lane & 31) << 3;               // 32 lanes x 8 elems = 256 cols
    int start = offs[wv];
    int n = cnt[wv];
    float acc[8] = {};
    int i = 0;
    for (; i + 8 <= n; i += 8) {
        int s0 = eidx[start + i + 0 + half];
        int s1 = eidx[start + i + 2 + half];
        int s2 = eidx[start + i + 4 + half];
        int s3 = eidx[start + i + 6 + half];
        bf16x8 v0 = *(const bf16x8*)(xb + (size_t)s0 * ldx + c);
        bf16x8 v1 = *(const bf16x8*)(xb + (size_t)s1 * ldx + c);
        bf16x8 v2 = *(const bf16x8*)(xb + (size_t)s2 * ldx + c);
        bf16x8 v3 = *(const bf16x8*)(xb + (size_t)s3 * ldx + c);
        #pragma unroll
        for (int j = 0; j < 8; j++)
            acc[j] += ((float)v0[j] + (float)v1[j]) + ((float)v2[j] + (float)v3[j]);
    }
    for (; i + 2 <= n; i += 2) {
        int s = eidx[start + i + half];
        bf16x8 v = *(const bf16x8*)(xb + (size_t)s * ldx + c);
        #pragma unroll
        for (int j = 0; j < 8; j++) acc[j] += (float)v[j];
    }
    if (i < n && half == 0) {
        int s = eidx[start + i];
        bf16x8 v = *(const bf16x8*)(xb + (size_t)s * ldx + c);
        #pragma unroll
        for (int j = 0; j < 8; j++) acc[j] += (float)v[j];
    }
    #pragma unroll
    for (int j = 0; j < 8; j++) acc[j] += __shfl_xor(acc[j], 32, 64);
    if (half == 0) {
        float inv = 1.0f / ((float)n + 1e-10f);
        int node = wv >> 2, r = wv & 3;
        bf16x8 o;
        #pragma unroll
        for (int j = 0; j < 8; j++) o[j] = (bf16_t)(acc[j] * inv);
        *(bf16x8*)(Aout + (size_t)node * lda + r * 256 + c) = o;
    }
}

// ---------------- segment mean, D=128: quarter-wave/edge, bf16x8, 8-deep unroll ----
__global__ void seg_mean128(const int* __restrict__ offs, const int* __restrict__ cnt,
                            const int* __restrict__ eidx,
                            const bf16_t* __restrict__ xb, int ldx,
                            bf16_t* __restrict__ Aout, int lda, int NSEG)
{
    int wv = (blockIdx.x << 2) + (threadIdx.x >> 6);
    if (wv >= NSEG) return;
    int lane = threadIdx.x & 63;
    int q = lane >> 4;                      // quarter 0..3
    int c = (lane & 15) << 3;               // 16 lanes x 8 elems = 128 cols
    int start = offs[wv];
    int n = cnt[wv];
    float acc[8] = {};
    int i = 0;
    for (; i + 8 <= n; i += 8) {
        int s0 = eidx[start + i + q];
        int s1 = eidx[start + i + 4 + q];
        bf16x8 v0 = *(const bf16x8*)(xb + (size_t)s0 * ldx + c);
        bf16x8 v1 = *(const bf16x8*)(xb + (size_t)s1 * ldx + c);
        #pragma unroll
        for (int j = 0; j < 8; j++) acc[j] += (float)v0[j] + (float)v1[j];
    }
    for (; i + 4 <= n; i += 4) {
        int s = eidx[start + i + q];
        bf16x8 v = *(const bf16x8*)(xb + (size_t)s * ldx + c);
        #pragma unroll
        for (int j = 0; j < 8; j++) acc[j] += (float)v[j];
    }
    if (q < n - i) {
        int s = eidx[start + i + q];
        bf16x8 v = *(const bf16x8*)(xb + (size_t)s * ldx + c);
        #pragma unroll
        for (int j = 0; j < 8; j++) acc[j] += (float)v[j];
    }
    #pragma unroll
    for (int j = 0; j < 8; j++) {
        acc[j] += __shfl_xor(acc[j], 16, 64);
        acc[j] += __shfl_xor(acc[j], 32, 64);
    }
    if (lane < 16) {
        float inv = 1.0f / ((float)n + 1e-10f);
        int node = wv >> 2, r = wv & 3;
        bf16x8 o;
        #pragma unroll
        for (int j = 0; j < 8; j++) o[j] = (bf16_t)(acc[j] * inv);
        *(bf16x8*)(Aout + (size_t)node * lda + r * 128 + c) = o;
    }
}

// x fp32 [N,128] -> bf16 into A1 columns 512..640 (ld 640)
__global__ void convert_x_k(const float* __restrict__ x, bf16_t* __restrict__ A1, int N)
{
    int t = blockIdx.x * blockDim.x + threadIdx.x;
    if (t >= N * 32) return;
    int row = t >> 5;
    int c = (t & 31) << 2;
    f32x4 v = *(const f32x4*)(x + (size_t)row * 128 + c);
    bf16x4 o;
    o[0] = (bf16_t)v[0]; o[1] = (bf16_t)v[1]; o[2] = (bf16_t)v[2]; o[3] = (bf16_t)v[3];
    *(bf16x4*)(A1 + (size_t)row * 640 + 512 + c) = o;
}

// Wt[(n0+n)*ldk + k0 + k] = (bf16) W[k, n];  W is [K,256] row-major
__global__ void transpose_w(const float* __restrict__ W, bf16_t* __restrict__ Wt,
                            int K, int ldk, int k0, int n0)
{
    int t = blockIdx.x * blockDim.x + threadIdx.x;
    if (t >= K * 256) return;
    int k = t >> 8, n = t & 255;
    Wt[(size_t)(n0 + n) * ldk + k0 + k] = (bf16_t)W[(size_t)k * 256 + n];
}

__global__ void prep_bias(const float* rb1, const float* lb1,
                          const float* rb2, const float* lb2,
                          const float* hpb1, const float* htb1,
                          const float* hpb2, const float* htb2,
                          float* bR1, float* bR2, float* bH1, float* bH2)
{
    int t = threadIdx.x;  // 256
    bR1[t] = rb1[t] + lb1[t];
    bR2[t] = rb2[t] + lb2[t];
    bH1[t] = hpb1[t]; bH1[256 + t] = htb1[t];
    bH2[t] = hpb2[t]; bH2[256 + t] = htb2[t];
}

extern "C" void kernel_launch(void* const* d_in, const int* in_sizes, int n_in,
                              void* d_out, int out_size, void* d_ws, size_t ws_size,
                              hipStream_t stream)
{
    const float* x       = (const float*)d_in[0];
    const int*   src     = (const int*)d_in[1];
    const int*   dst     = (const int*)d_in[2];
    const int*   rel     = (const int*)d_in[3];
    const float* rel_w1  = (const float*)d_in[4];
    const float* rel_b1  = (const float*)d_in[5];
    const float* loop_w1 = (const float*)d_in[6];
    const float* loop_b1 = (const float*)d_in[7];
    const float* hp_w1   = (const float*)d_in[8];
    const float* hp_b1   = (const float*)d_in[9];
    const float* ht_w1   = (const float*)d_in[10];
    const float* ht_b1   = (const float*)d_in[11];
    const float* rel_w2  = (const float*)d_in[12];
    const float* rel_b2  = (const float*)d_in[13];
    const float* loop_w2 = (const float*)d_in[14];
    const float* loop_b2 = (const float*)d_in[15];
    const float* hp_w2   = (const float*)d_in[16];
    const float* hp_b2   = (const float*)d_in[17];
    const float* ht_w2   = (const float*)d_in[18];
    const float* ht_b2   = (const float*)d_in[19];

    const int N = in_sizes[0] / 128;   // 50000
    const int E = in_sizes[1];         // 800000
    const int NSEG = N * 4;            // 200000
    const int NCHUNK = (NSEG + 255) / 256;   // 782
    float* out = (float*)d_out;

    char* ws = (char*)d_ws;
    size_t off = 0;
    auto alloc = [&](size_t bytes) {
        void* p = ws + off;
        off += (bytes + 255) & ~(size_t)255;
        return p;
    };
    int*    cnt    = (int*)alloc((size_t)NSEG * 4);
    int*    offs   = (int*)alloc((size_t)NSEG * 4);
    int*    cursor = (int*)alloc((size_t)NSEG * 4);
    int*    chunkS = (int*)alloc(4096);
    int*    eidx   = (int*)alloc((size_t)E * 4);
    bf16_t* A1     = (bf16_t*)alloc((size_t)N * 640 * 2);    // [update1 | x_bf16]
    bf16_t* A2     = (bf16_t*)alloc((size_t)N * 1280 * 2);   // [update2 | h1']
    bf16_t* h      = (bf16_t*)alloc((size_t)N * 256 * 2);
    bf16_t* W1t    = (bf16_t*)alloc((size_t)256 * 640 * 2);
    bf16_t* W2t    = (bf16_t*)alloc((size_t)256 * 1280 * 2);
    bf16_t* Wh1t   = (bf16_t*)alloc((size_t)512 * 256 * 2);
    bf16_t* Wh2t   = (bf16_t*)alloc((size_t)512 * 256 * 2);
    float*  bR1    = (float*)alloc(256 * 4);
    float*  bR2    = (float*)alloc(256 * 4);
    float*  bH1    = (float*)alloc(512 * 4);
    float*  bH2    = (float*)alloc(512 * 4);

    dim3 blk(256);
    const int NTM = (N + BM - 1) / BM;       // 391
    const int supers = (NTM + 7) / 8;        // 49
    const int gridRGC = supers * 8 * 2;      // 784
    const int gridHW  = supers * 8 * 4;      // 1568 (4 strips of 64 P+G cols)

    // ---- weight/bias prep ----
    transpose_w<<<dim3(512), blk, 0, stream>>>(rel_w1, W1t, 512, 640, 0, 0);
    transpose_w<<<dim3(128), blk, 0, stream>>>(loop_w1, W1t, 128, 640, 512, 0);
    transpose_w<<<dim3(1024), blk, 0, stream>>>(rel_w2, W2t, 1024, 1280, 0, 0);
    transpose_w<<<dim3(256), blk, 0, stream>>>(loop_w2, W2t, 256, 1280, 1024, 0);
    transpose_w<<<dim3(256), blk, 0, stream>>>(hp_w1, Wh1t, 256, 256, 0, 0);
    transpose_w<<<dim3(256), blk, 0, stream>>>(ht_w1, Wh1t, 256, 256, 0, 256);
    transpose_w<<<dim3(256), blk, 0, stream>>>(hp_w2, Wh2t, 256, 256, 0, 0);
    transpose_w<<<dim3(256), blk, 0, stream>>>(ht_w2, Wh2t, 256, 256, 0, 256);
    prep_bias<<<dim3(1), blk, 0, stream>>>(rel_b1, loop_b1, rel_b2, loop_b2,
                                           hp_b1, ht_b1, hp_b2, ht_b2,
                                           bR1, bR2, bH1, bH2);
    convert_x_k<<<dim3((N * 32 + 255) / 256), blk, 0, stream>>>(x, A1, N);

    // ---- CSR build (shared by both layers) ----
    hipMemsetAsync(cnt, 0, (size_t)NSEG * 4, stream);
    count_k<<<dim3((E + 255) / 256), blk, 0, stream>>>(dst, rel, cnt, E);
    scan_partial<<<dim3(NCHUNK), blk, 0, stream>>>(cnt, offs, chunkS, NSEG);
    scan_chunks<<<dim3(1), dim3(1024), 0, stream>>>(chunkS, NCHUNK);
    scan_add<<<dim3(NCHUNK), blk, 0, stream>>>(offs, chunkS, cursor, NSEG);
    fill_k<<<dim3((E + 255) / 256), blk, 0, stream>>>(src, dst, rel, cursor, eidx, E);

    // ---- layer 1 ----
    seg_mean128<<<dim3((NSEG + 3) / 4), blk, 0, stream>>>(offs, cnt, eidx,
                                                          A1 + 512, 640, A1, 640, NSEG);
    gemm_k<<<dim3(gridRGC), blk, 0, stream>>>(A1, 640, N, W1t, 640,
                                              bR1, 1, h, 256, 0, NTM, 2);
    gemm_hw2<<<dim3(gridHW), blk, 0, stream>>>(h, N, Wh1t, bH1,
                                               A2, 1280, 1024, nullptr, NTM);

    // ---- layer 2 ----
    seg_mean256<<<dim3((NSEG + 3) / 4), blk, 0, stream>>>(offs, cnt, eidx,
                                                          A2 + 1024, 1280, A2, 1280, NSEG);
    gemm_k<<<dim3(gridRGC), blk, 0, stream>>>(A2, 1280, N, W2t, 1280,
                                              bR2, 1, h, 256, 0, NTM, 2);
    gemm_hw2<<<dim3(gridHW), blk, 0, stream>>>(h, N, Wh2t, bH2,
                                               nullptr, 0, 0, out, NTM);
}